// Round 1
// 212.230 us; speedup vs baseline: 1.0269x; 1.0269x over previous
//
#include <hip/hip_runtime.h>
#include <math.h>

// HermiteFuncs: x[B=32, n=64, N=4096] fp32 -> psi[B, n, R=6, N] fp32
// s = tanh(x)*sqrt(13); g = exp(-s^2/2); c = pi^(-1/4)
// psi0 = c*g; psi1 = sqrt(2)*c*s*g; psi_k = sqrt(2/k)*s*psi_{k-1} - sqrt((k-1)/k)*psi_{k-2}
//
// Memory-bound: read 33.6 MB, write 201 MB -> ~37 us @ 6.4 TB/s kernel floor.
// R3 change: REVERT nontemporal stores -> plain stores. Evidence: the harness's
// fillBufferAligned memset sustains 6.4 TB/s of pure writes with plain stores,
// while this kernel's nt-store path was achieving only ~2.5 TB/s. The nt flag
// (TCC no-allocate) defeats L2 full-line dirty allocation / write combining;
// plain wave-level 1KB-contiguous stores dirty whole 128B lines and stream out
// at full rate.

typedef float vf4 __attribute__((ext_vector_type(4)));

__global__ __launch_bounds__(256) void hermite_kernel(
    const vf4* __restrict__ x, float* __restrict__ out, int total4)
{
    int t = blockIdx.x * blockDim.x + threadIdx.x;
    if (t >= total4) return;

    int row = t >> 10;          // b*64 + n   (N/4 = 1024 float4 per row)
    int col = t & 1023;

    vf4 xv = __builtin_nontemporal_load(x + t);

    const float SQRT13 = 3.6055512754639896f;   // sqrt(2*6+1)
    const float C0     = 0.7511255444649425f;   // pi^(-1/4)
    const float SQRT2C = 1.0622519320271968f;   // sqrt(2)*c

    const float a2 = 1.0f,               b2 = 0.7071067811865476f;
    const float a3 = 0.816496580927726f, b3 = 0.816496580927726f;
    const float a4 = 0.7071067811865476f, b4 = 0.8660254037844386f;
    const float a5 = 0.6324555320336759f, b5 = 0.8944271909999159f;

    vf4 p0, p1, p2, p3, p4, p5;
    float* f0 = (float*)&p0; float* f1 = (float*)&p1; float* f2 = (float*)&p2;
    float* f3 = (float*)&p3; float* f4 = (float*)&p4; float* f5 = (float*)&p5;

#pragma unroll
    for (int j = 0; j < 4; ++j) {
        float xval = xv[j];
        // fast tanh: 1 - 2/(e^{2x}+1); saturates correctly for |x| large
        float e2x = __expf(2.0f * xval);
        float r   = __builtin_amdgcn_rcpf(e2x + 1.0f);
        float th  = fmaf(-2.0f, r, 1.0f);
        float s   = th * SQRT13;
        float g   = __expf(-0.5f * s * s);
        float q0 = C0 * g;
        float q1 = SQRT2C * s * g;
        float q2 = a2 * s * q1 - b2 * q0;
        float q3 = a3 * s * q2 - b3 * q1;
        float q4 = a4 * s * q3 - b4 * q2;
        float q5 = a5 * s * q4 - b5 * q3;
        f0[j] = q0; f1[j] = q1; f2[j] = q2; f3[j] = q3; f4[j] = q4; f5[j] = q5;
    }

    vf4* ob = (vf4*)(out + (size_t)row * 6 * 4096) + col;
    ob[0]    = p0;
    ob[1024] = p1;
    ob[2048] = p2;
    ob[3072] = p3;
    ob[4096] = p4;
    ob[5120] = p5;
}

extern "C" void kernel_launch(void* const* d_in, const int* in_sizes, int n_in,
                              void* d_out, int out_size, void* d_ws, size_t ws_size,
                              hipStream_t stream) {
    const vf4* x = (const vf4*)d_in[0];
    float* out = (float*)d_out;
    int total4 = in_sizes[0] / 4;            // 2097152
    int block = 256;
    int grid = (total4 + block - 1) / block; // 8192
    hermite_kernel<<<grid, block, 0, stream>>>(x, out, total4);
}